// Round 1
// baseline (3997.647 us; speedup 1.0000x reference)
//
#include <hip/hip_runtime.h>
#include <math.h>

// GCN forward: GCNConv(6->4, self-loops, sym-norm) -> tanh -> mean-pool -> fc1(4->64)+relu -> fc3(64->10)
// Key identity: agg[c] = dinv[c] * ( sum_{edges r->c} p[r] + p[c] ) + conv_b, where p[i] = h[i]*dinv[i].

__global__ void k_deg(const int* __restrict__ col, int n_edges, int* __restrict__ deg) {
    int t = blockIdx.x * blockDim.x + threadIdx.x;
    int base = t * 4;
    if (base + 4 <= n_edges) {
        int4 c = *(const int4*)(col + base);
        atomicAdd(&deg[c.x], 1);
        atomicAdd(&deg[c.y], 1);
        atomicAdd(&deg[c.z], 1);
        atomicAdd(&deg[c.w], 1);
    } else {
        for (int e = base; e < n_edges; ++e) atomicAdd(&deg[col[e]], 1);
    }
}

__global__ void k_node(const float* __restrict__ x, const float* __restrict__ conv_w,
                       const int* __restrict__ deg, float4* __restrict__ p, int n) {
    int i = blockIdx.x * blockDim.x + threadIdx.x;
    if (i >= n) return;
    const float* xr = x + (size_t)i * 6;
    float2 a = *(const float2*)xr;
    float2 b = *(const float2*)(xr + 2);
    float2 c = *(const float2*)(xr + 4);
    float xv[6] = {a.x, a.y, b.x, b.y, c.x, c.y};
    float dinv = rsqrtf((float)(deg[i] + 1));   // +1 self-loop
    float h0 = 0.f, h1 = 0.f, h2 = 0.f, h3 = 0.f;
#pragma unroll
    for (int j = 0; j < 6; ++j) {
        h0 += xv[j] * conv_w[j];
        h1 += xv[j] * conv_w[6 + j];
        h2 += xv[j] * conv_w[12 + j];
        h3 += xv[j] * conv_w[18 + j];
    }
    float4 o;
    o.x = h0 * dinv; o.y = h1 * dinv; o.z = h2 * dinv; o.w = h3 * dinv;
    p[i] = o;
}

__global__ void k_scatter(const int* __restrict__ row, const int* __restrict__ col, int n_edges,
                          const float4* __restrict__ p, float* __restrict__ S) {
    int t = blockIdx.x * blockDim.x + threadIdx.x;
    int base = t * 2;
    if (base + 2 <= n_edges) {
        int2 r = *(const int2*)(row + base);
        int2 c = *(const int2*)(col + base);
        float4 p0 = p[r.x];
        float4 p1 = p[r.y];
        float* s0 = S + 4 * c.x;
        unsafeAtomicAdd(s0 + 0, p0.x);
        unsafeAtomicAdd(s0 + 1, p0.y);
        unsafeAtomicAdd(s0 + 2, p0.z);
        unsafeAtomicAdd(s0 + 3, p0.w);
        float* s1 = S + 4 * c.y;
        unsafeAtomicAdd(s1 + 0, p1.x);
        unsafeAtomicAdd(s1 + 1, p1.y);
        unsafeAtomicAdd(s1 + 2, p1.z);
        unsafeAtomicAdd(s1 + 3, p1.w);
    } else {
        for (int e = base; e < n_edges; ++e) {
            int r = row[e], c = col[e];
            float4 pv = p[r];
            float* s = S + 4 * c;
            unsafeAtomicAdd(s + 0, pv.x);
            unsafeAtomicAdd(s + 1, pv.y);
            unsafeAtomicAdd(s + 2, pv.z);
            unsafeAtomicAdd(s + 3, pv.w);
        }
    }
}

__global__ void k_reduce(const float4* __restrict__ S4, const float4* __restrict__ p,
                         const int* __restrict__ deg, const float* __restrict__ conv_b,
                         int n, float* __restrict__ gsum) {
    int i = blockIdx.x * blockDim.x + threadIdx.x;
    float4 v = {0.f, 0.f, 0.f, 0.f};
    if (i < n) {
        float dinv = rsqrtf((float)(deg[i] + 1));
        float4 s = S4[i];
        float4 pp = p[i];
        v.x = tanhf(dinv * (s.x + pp.x) + conv_b[0]);
        v.y = tanhf(dinv * (s.y + pp.y) + conv_b[1]);
        v.z = tanhf(dinv * (s.z + pp.z) + conv_b[2]);
        v.w = tanhf(dinv * (s.w + pp.w) + conv_b[3]);
    }
#pragma unroll
    for (int off = 32; off > 0; off >>= 1) {
        v.x += __shfl_down(v.x, off);
        v.y += __shfl_down(v.y, off);
        v.z += __shfl_down(v.z, off);
        v.w += __shfl_down(v.w, off);
    }
    __shared__ float4 lds[4];
    int lane = threadIdx.x & 63;
    int w = threadIdx.x >> 6;
    if (lane == 0) lds[w] = v;
    __syncthreads();
    if (threadIdx.x == 0) {
        float4 tt = lds[0];
        for (int k = 1; k < 4; ++k) {
            tt.x += lds[k].x; tt.y += lds[k].y; tt.z += lds[k].z; tt.w += lds[k].w;
        }
        unsafeAtomicAdd(&gsum[0], tt.x);
        unsafeAtomicAdd(&gsum[1], tt.y);
        unsafeAtomicAdd(&gsum[2], tt.z);
        unsafeAtomicAdd(&gsum[3], tt.w);
    }
}

__global__ void k_head(const float* __restrict__ gsum,
                       const float* __restrict__ fc1w, const float* __restrict__ fc1b,
                       const float* __restrict__ fc3w, const float* __restrict__ fc3b,
                       float* __restrict__ out, int n) {
    __shared__ float hdn[64];
    int t = threadIdx.x;
    float g[4];
    float inv_n = 1.0f / (float)n;
#pragma unroll
    for (int j = 0; j < 4; ++j) g[j] = gsum[j] * inv_n;
    if (t < 64) {
        float a = fc1b[t];
#pragma unroll
        for (int j = 0; j < 4; ++j) a += g[j] * fc1w[t * 4 + j];
        hdn[t] = fmaxf(a, 0.f);
    }
    __syncthreads();
    if (t < 10) {
        float a = fc3b[t];
#pragma unroll
        for (int k = 0; k < 64; ++k) a += hdn[k] * fc3w[t * 64 + k];
        out[t] = a;
    }
}

extern "C" void kernel_launch(void* const* d_in, const int* in_sizes, int n_in,
                              void* d_out, int out_size, void* d_ws, size_t ws_size,
                              hipStream_t stream) {
    const float* x      = (const float*)d_in[0];
    const int*   ei     = (const int*)d_in[1];   // [2, E] int32
    const float* conv_w = (const float*)d_in[2];
    const float* conv_b = (const float*)d_in[3];
    const float* fc1w   = (const float*)d_in[4];
    const float* fc1b   = (const float*)d_in[5];
    const float* fc3w   = (const float*)d_in[6];
    const float* fc3b   = (const float*)d_in[7];

    int n = in_sizes[0] / 6;
    int E = in_sizes[1] / 2;

    // ws layout: deg[n] int | S[4n] float | gsum[4] float | p[4n] float
    char* ws = (char*)d_ws;
    size_t off = 0;
    int* deg = (int*)(ws + off);
    off += (size_t)n * sizeof(int);
    off = (off + 15) & ~(size_t)15;
    float* S = (float*)(ws + off);
    off += (size_t)n * 4 * sizeof(float);
    float* gsum = (float*)(ws + off);
    size_t zero_end = off + 4 * sizeof(float);
    off = zero_end;
    off = (off + 15) & ~(size_t)15;
    float4* p = (float4*)(ws + off);

    hipMemsetAsync(d_ws, 0, zero_end, stream);

    const int* row = ei;       // edge_index[0] = source
    const int* col = ei + E;   // edge_index[1] = target

    int t1 = (E + 3) / 4;
    k_deg<<<(t1 + 255) / 256, 256, 0, stream>>>(col, E, deg);
    k_node<<<(n + 255) / 256, 256, 0, stream>>>(x, conv_w, deg, p, n);
    int t3 = (E + 1) / 2;
    k_scatter<<<(t3 + 255) / 256, 256, 0, stream>>>(row, col, E, p, S);
    k_reduce<<<(n + 255) / 256, 256, 0, stream>>>((const float4*)S, p, deg, conv_b, n, gsum);
    k_head<<<1, 64, 0, stream>>>(gsum, fc1w, fc1b, fc3w, fc3b, (float*)d_out, n);
}

// Round 2
// 902.840 us; speedup vs baseline: 4.4279x; 4.4279x over previous
//
#include <hip/hip_runtime.h>
#include <math.h>

// GCN forward: GCNConv(6->4, self-loops, sym-norm) -> tanh -> mean-pool -> fc1+relu -> fc3
// agg[c] = dinv[c] * ( sum_{edges r->c} p[r] + p[c] ) + conv_b, p[i] = (W x[i]) * dinv[i]
//
// R2 strategy: global f32 atomics caused 2 GB HBM write-through (32 B/atomic).
// Replace with target-partition binning (1024 nodes/partition) + LDS-tile accumulation.

constexpr int NP = 1024;        // nodes per partition
constexpr int SHIFT = 10;
constexpr unsigned MASK = 1023;
constexpr int NPART_MAX = 1024; // LDS counter array bound
constexpr int EPB = 16384;      // edges per k_bin block

// ---------------- binning path ----------------

__global__ void k_bin(const int* __restrict__ row, const int* __restrict__ col, int E,
                      int P, int cap, int* __restrict__ cursor, unsigned* __restrict__ binned) {
    __shared__ int lcount[NPART_MAX];
    __shared__ int lbase[NPART_MAX];
    int tid = threadIdx.x;
    for (int i = tid; i < P; i += blockDim.x) lcount[i] = 0;
    __syncthreads();
    int start = blockIdx.x * EPB;
    int end = min(start + EPB, E);
    for (int e = start + tid; e < end; e += blockDim.x) {
        int c = col[e];
        atomicAdd(&lcount[c >> SHIFT], 1);
    }
    __syncthreads();
    for (int i = tid; i < P; i += blockDim.x) {
        int c = lcount[i];
        lbase[i] = (c > 0) ? atomicAdd(&cursor[i], c) : 0;
        lcount[i] = 0;
    }
    __syncthreads();
    for (int e = start + tid; e < end; e += blockDim.x) {
        int r = row[e];
        int c = col[e];
        int part = c >> SHIFT;
        int slot = lbase[part] + atomicAdd(&lcount[part], 1);
        if (slot < cap)
            binned[(size_t)part * cap + slot] = ((unsigned)r << SHIFT) | ((unsigned)c & MASK);
    }
}

// per-partition: deg from bin (LDS), then p = (W x)*dinv, store p + dinv
__global__ void k_part_node(const unsigned* __restrict__ binned, const int* __restrict__ cursor,
                            int cap, const float* __restrict__ x, const float* __restrict__ conv_w,
                            int n, float4* __restrict__ p4, float* __restrict__ dinvg) {
    __shared__ int degs[NP];
    __shared__ float w[24];
    int part = blockIdx.x;
    int tid = threadIdx.x;
    if (tid < 24) w[tid] = conv_w[tid];
    for (int i = tid; i < NP; i += blockDim.x) degs[i] = 0;
    __syncthreads();
    int cnt = min(cursor[part], cap);
    const unsigned* bin = binned + (size_t)part * cap;
    for (int e = tid; e < cnt; e += blockDim.x)
        atomicAdd(&degs[bin[e] & MASK], 1);
    __syncthreads();
    int base = part * NP;
    for (int i = tid; i < NP; i += blockDim.x) {
        int node = base + i;
        if (node >= n) continue;
        float dinv = rsqrtf((float)(degs[i] + 1));   // +1 self-loop
        const float* xr = x + (size_t)node * 6;
        float2 a = *(const float2*)xr;
        float2 b = *(const float2*)(xr + 2);
        float2 cc = *(const float2*)(xr + 4);
        float xv[6] = {a.x, a.y, b.x, b.y, cc.x, cc.y};
        float h0 = 0.f, h1 = 0.f, h2 = 0.f, h3 = 0.f;
#pragma unroll
        for (int j = 0; j < 6; ++j) {
            h0 += xv[j] * w[j];
            h1 += xv[j] * w[6 + j];
            h2 += xv[j] * w[12 + j];
            h3 += xv[j] * w[18 + j];
        }
        float4 o;
        o.x = h0 * dinv; o.y = h1 * dinv; o.z = h2 * dinv; o.w = h3 * dinv;
        p4[node] = o;
        dinvg[node] = dinv;
    }
}

// per-partition: accumulate p[row] into LDS tile, tanh, block-reduce -> gsum
__global__ void k_acc(const unsigned* __restrict__ binned, const int* __restrict__ cursor,
                      int cap, const float4* __restrict__ p4, const float* __restrict__ dinvg,
                      const float* __restrict__ conv_b, int n, float* __restrict__ gsum) {
    __shared__ float S[NP * 4];
    int part = blockIdx.x;
    int tid = threadIdx.x;
    for (int i = tid; i < NP * 4; i += blockDim.x) S[i] = 0.f;
    __syncthreads();
    int cnt = min(cursor[part], cap);
    const unsigned* bin = binned + (size_t)part * cap;
    for (int e = tid; e < cnt; e += blockDim.x) {
        unsigned v = bin[e];
        int r = (int)(v >> SHIFT);
        int local = (int)(v & MASK);
        float4 pv = p4[r];
        atomicAdd(&S[local * 4 + 0], pv.x);
        atomicAdd(&S[local * 4 + 1], pv.y);
        atomicAdd(&S[local * 4 + 2], pv.z);
        atomicAdd(&S[local * 4 + 3], pv.w);
    }
    __syncthreads();
    float b0 = conv_b[0], b1 = conv_b[1], b2 = conv_b[2], b3 = conv_b[3];
    float4 acc = {0.f, 0.f, 0.f, 0.f};
    int base = part * NP;
    for (int i = tid; i < NP; i += blockDim.x) {
        int node = base + i;
        if (node >= n) continue;
        float di = dinvg[node];
        float4 pv = p4[node];
        acc.x += tanhf(di * (S[i * 4 + 0] + pv.x) + b0);
        acc.y += tanhf(di * (S[i * 4 + 1] + pv.y) + b1);
        acc.z += tanhf(di * (S[i * 4 + 2] + pv.z) + b2);
        acc.w += tanhf(di * (S[i * 4 + 3] + pv.w) + b3);
    }
#pragma unroll
    for (int off = 32; off > 0; off >>= 1) {
        acc.x += __shfl_down(acc.x, off);
        acc.y += __shfl_down(acc.y, off);
        acc.z += __shfl_down(acc.z, off);
        acc.w += __shfl_down(acc.w, off);
    }
    __shared__ float4 red[4];
    int lane = tid & 63, wv = tid >> 6;
    if (lane == 0) red[wv] = acc;
    __syncthreads();
    if (tid == 0) {
        float4 t = red[0];
        for (int k = 1; k < 4; ++k) {
            t.x += red[k].x; t.y += red[k].y; t.z += red[k].z; t.w += red[k].w;
        }
        unsafeAtomicAdd(&gsum[0], t.x);
        unsafeAtomicAdd(&gsum[1], t.y);
        unsafeAtomicAdd(&gsum[2], t.z);
        unsafeAtomicAdd(&gsum[3], t.w);
    }
}

__global__ void k_head(const float* __restrict__ gsum,
                       const float* __restrict__ fc1w, const float* __restrict__ fc1b,
                       const float* __restrict__ fc3w, const float* __restrict__ fc3b,
                       float* __restrict__ out, int n) {
    __shared__ float hdn[64];
    int t = threadIdx.x;
    float g[4];
    float inv_n = 1.0f / (float)n;
#pragma unroll
    for (int j = 0; j < 4; ++j) g[j] = gsum[j] * inv_n;
    if (t < 64) {
        float a = fc1b[t];
#pragma unroll
        for (int j = 0; j < 4; ++j) a += g[j] * fc1w[t * 4 + j];
        hdn[t] = fmaxf(a, 0.f);
    }
    __syncthreads();
    if (t < 10) {
        float a = fc3b[t];
#pragma unroll
        for (int k = 0; k < 64; ++k) a += hdn[k] * fc3w[t * 64 + k];
        out[t] = a;
    }
}

// ---------------- fallback path (round-1, global atomics) ----------------

__global__ void k_deg(const int* __restrict__ col, int n_edges, int* __restrict__ deg) {
    int t = blockIdx.x * blockDim.x + threadIdx.x;
    int base = t * 4;
    if (base + 4 <= n_edges) {
        int4 c = *(const int4*)(col + base);
        atomicAdd(&deg[c.x], 1); atomicAdd(&deg[c.y], 1);
        atomicAdd(&deg[c.z], 1); atomicAdd(&deg[c.w], 1);
    } else {
        for (int e = base; e < n_edges; ++e) atomicAdd(&deg[col[e]], 1);
    }
}

__global__ void k_node(const float* __restrict__ x, const float* __restrict__ conv_w,
                       const int* __restrict__ deg, float4* __restrict__ p, int n) {
    int i = blockIdx.x * blockDim.x + threadIdx.x;
    if (i >= n) return;
    const float* xr = x + (size_t)i * 6;
    float2 a = *(const float2*)xr;
    float2 b = *(const float2*)(xr + 2);
    float2 c = *(const float2*)(xr + 4);
    float xv[6] = {a.x, a.y, b.x, b.y, c.x, c.y};
    float dinv = rsqrtf((float)(deg[i] + 1));
    float h0 = 0.f, h1 = 0.f, h2 = 0.f, h3 = 0.f;
#pragma unroll
    for (int j = 0; j < 6; ++j) {
        h0 += xv[j] * conv_w[j];
        h1 += xv[j] * conv_w[6 + j];
        h2 += xv[j] * conv_w[12 + j];
        h3 += xv[j] * conv_w[18 + j];
    }
    float4 o; o.x = h0 * dinv; o.y = h1 * dinv; o.z = h2 * dinv; o.w = h3 * dinv;
    p[i] = o;
}

__global__ void k_scatter(const int* __restrict__ row, const int* __restrict__ col, int n_edges,
                          const float4* __restrict__ p, float* __restrict__ S) {
    int t = blockIdx.x * blockDim.x + threadIdx.x;
    int base = t * 2;
    if (base + 2 <= n_edges) {
        int2 r = *(const int2*)(row + base);
        int2 c = *(const int2*)(col + base);
        float4 p0 = p[r.x], p1 = p[r.y];
        float* s0 = S + 4 * c.x;
        unsafeAtomicAdd(s0 + 0, p0.x); unsafeAtomicAdd(s0 + 1, p0.y);
        unsafeAtomicAdd(s0 + 2, p0.z); unsafeAtomicAdd(s0 + 3, p0.w);
        float* s1 = S + 4 * c.y;
        unsafeAtomicAdd(s1 + 0, p1.x); unsafeAtomicAdd(s1 + 1, p1.y);
        unsafeAtomicAdd(s1 + 2, p1.z); unsafeAtomicAdd(s1 + 3, p1.w);
    } else {
        for (int e = base; e < n_edges; ++e) {
            int r = row[e], c = col[e];
            float4 pv = p[r];
            float* s = S + 4 * c;
            unsafeAtomicAdd(s + 0, pv.x); unsafeAtomicAdd(s + 1, pv.y);
            unsafeAtomicAdd(s + 2, pv.z); unsafeAtomicAdd(s + 3, pv.w);
        }
    }
}

__global__ void k_reduce(const float4* __restrict__ S4, const float4* __restrict__ p,
                         const int* __restrict__ deg, const float* __restrict__ conv_b,
                         int n, float* __restrict__ gsum) {
    int i = blockIdx.x * blockDim.x + threadIdx.x;
    float4 v = {0.f, 0.f, 0.f, 0.f};
    if (i < n) {
        float dinv = rsqrtf((float)(deg[i] + 1));
        float4 s = S4[i];
        float4 pp = p[i];
        v.x = tanhf(dinv * (s.x + pp.x) + conv_b[0]);
        v.y = tanhf(dinv * (s.y + pp.y) + conv_b[1]);
        v.z = tanhf(dinv * (s.z + pp.z) + conv_b[2]);
        v.w = tanhf(dinv * (s.w + pp.w) + conv_b[3]);
    }
#pragma unroll
    for (int off = 32; off > 0; off >>= 1) {
        v.x += __shfl_down(v.x, off);
        v.y += __shfl_down(v.y, off);
        v.z += __shfl_down(v.z, off);
        v.w += __shfl_down(v.w, off);
    }
    __shared__ float4 lds[4];
    int lane = threadIdx.x & 63, w = threadIdx.x >> 6;
    if (lane == 0) lds[w] = v;
    __syncthreads();
    if (threadIdx.x == 0) {
        float4 tt = lds[0];
        for (int k = 1; k < 4; ++k) {
            tt.x += lds[k].x; tt.y += lds[k].y; tt.z += lds[k].z; tt.w += lds[k].w;
        }
        unsafeAtomicAdd(&gsum[0], tt.x); unsafeAtomicAdd(&gsum[1], tt.y);
        unsafeAtomicAdd(&gsum[2], tt.z); unsafeAtomicAdd(&gsum[3], tt.w);
    }
}

// ---------------- launch ----------------

extern "C" void kernel_launch(void* const* d_in, const int* in_sizes, int n_in,
                              void* d_out, int out_size, void* d_ws, size_t ws_size,
                              hipStream_t stream) {
    const float* x      = (const float*)d_in[0];
    const int*   ei     = (const int*)d_in[1];
    const float* conv_w = (const float*)d_in[2];
    const float* conv_b = (const float*)d_in[3];
    const float* fc1w   = (const float*)d_in[4];
    const float* fc1b   = (const float*)d_in[5];
    const float* fc3w   = (const float*)d_in[6];
    const float* fc3b   = (const float*)d_in[7];

    int n = in_sizes[0] / 6;
    int E = in_sizes[1] / 2;
    const int* row = ei;       // edge_index[0] = source
    const int* col = ei + E;   // edge_index[1] = target

    int P = (n + NP - 1) / NP;
    int avg = (E + P - 1) / P;
    int cap = ((avg + avg / 8 + 2048) + 15) & ~15;

    // ws layout (binning path): cursor[P] | gsum[4] | dinv[n] | p4[n] | binned[P*cap]
    size_t off = 0;
    size_t cursor_off = off;          off += (size_t)P * sizeof(int);
    off = (off + 15) & ~(size_t)15;
    size_t gsum_off = off;            off += 4 * sizeof(float);
    size_t zero_end = off;
    off = (off + 15) & ~(size_t)15;
    size_t dinv_off = off;            off += (size_t)n * sizeof(float);
    off = (off + 15) & ~(size_t)15;
    size_t p_off = off;               off += (size_t)n * sizeof(float4);
    off = (off + 15) & ~(size_t)15;
    size_t bin_off = off;             off += (size_t)P * cap * sizeof(unsigned);
    size_t need = off;

    char* ws = (char*)d_ws;
    bool use_bin = (ws_size >= need) && (P <= NPART_MAX) && (n < (1 << 22));

    if (use_bin) {
        int* cursor = (int*)(ws + cursor_off);
        float* gsum = (float*)(ws + gsum_off);
        float* dinvg = (float*)(ws + dinv_off);
        float4* p4 = (float4*)(ws + p_off);
        unsigned* binned = (unsigned*)(ws + bin_off);

        hipMemsetAsync(d_ws, 0, zero_end, stream);
        int bin_blocks = (E + EPB - 1) / EPB;
        k_bin<<<bin_blocks, 256, 0, stream>>>(row, col, E, P, cap, cursor, binned);
        k_part_node<<<P, 256, 0, stream>>>(binned, cursor, cap, x, conv_w, n, p4, dinvg);
        k_acc<<<P, 256, 0, stream>>>(binned, cursor, cap, p4, dinvg, conv_b, n, gsum);
        k_head<<<1, 64, 0, stream>>>(gsum, fc1w, fc1b, fc3w, fc3b, (float*)d_out, n);
    } else {
        // fallback: round-1 global-atomic path
        size_t o = 0;
        int* deg = (int*)(ws + o);      o += (size_t)n * sizeof(int);
        o = (o + 15) & ~(size_t)15;
        float* S = (float*)(ws + o);    o += (size_t)n * 4 * sizeof(float);
        float* gsum = (float*)(ws + o);
        size_t zend = o + 4 * sizeof(float);
        o = (zend + 15) & ~(size_t)15;
        float4* p = (float4*)(ws + o);

        hipMemsetAsync(d_ws, 0, zend, stream);
        int t1 = (E + 3) / 4;
        k_deg<<<(t1 + 255) / 256, 256, 0, stream>>>(col, E, deg);
        k_node<<<(n + 255) / 256, 256, 0, stream>>>(x, conv_w, deg, p, n);
        int t3 = (E + 1) / 2;
        k_scatter<<<(t3 + 255) / 256, 256, 0, stream>>>(row, col, E, p, S);
        k_reduce<<<(n + 255) / 256, 256, 0, stream>>>((const float4*)S, p, deg, conv_b, n, gsum);
        k_head<<<1, 64, 0, stream>>>(gsum, fc1w, fc1b, fc3w, fc3b, (float*)d_out, n);
    }
}

// Round 3
// 668.156 us; speedup vs baseline: 5.9831x; 1.3512x over previous
//
#include <hip/hip_runtime.h>
#include <math.h>

// GCN forward: GCNConv(6->4, self-loops, sym-norm) -> tanh -> mean-pool -> fc1+relu -> fc3
// agg[c] = dinv[c] * ( sum_{edges r->c} p[r] + p[c] ) + conv_b, p[i] = (W x[i]) * dinv[i]
//
// R3: (a) k_bin block-local counting sort -> coalesced flush (R2 wrote 405 MB for a
// 64 MB payload via scattered 4 B stores); (b) 1024-thread blocks for the per-partition
// kernels (R2 ran 8 waves/CU -> latency-exposed).

constexpr int NP = 1024;        // nodes per partition
constexpr int SHIFT = 10;
constexpr unsigned MASK = 1023;
constexpr int NPART_MAX = 512;  // scan width bound; P = ceil(500k/1024) = 489
constexpr int EPB = 8192;       // edges per k_bin block
constexpr int BINB = 512;       // k_bin block size

// ---------------- binning path ----------------

__global__ __launch_bounds__(BINB) void k_bin(const int* __restrict__ row,
                                              const int* __restrict__ col, int E,
                                              int P, int cap, int* __restrict__ cursor,
                                              unsigned* __restrict__ binned) {
    __shared__ unsigned lbuf[EPB];          // 32 KB, sorted-by-partition edge buffer
    __shared__ int lcount[NPART_MAX];
    __shared__ int lbase[NPART_MAX];        // exclusive scan of lcount
    __shared__ int gbase[NPART_MAX];        // reserved global base per partition
    __shared__ int lpos[NPART_MAX];
    __shared__ int sc[NPART_MAX];

    int t = threadIdx.x;
    int start = blockIdx.x * EPB;
    int end = min(start + EPB, E);

    for (int i = t; i < NPART_MAX; i += BINB) { lcount[i] = 0; lpos[i] = 0; }
    __syncthreads();

    // phase 1: count per partition
    for (int e = start + t; e < end; e += BINB)
        atomicAdd(&lcount[col[e] >> SHIFT], 1);
    __syncthreads();

    // phase 2: exclusive scan (Hillis-Steele, 512 wide)
    sc[t] = lcount[t];
    __syncthreads();
    for (int off = 1; off < NPART_MAX; off <<= 1) {
        int v = (t >= off) ? sc[t - off] : 0;
        __syncthreads();
        sc[t] += v;
        __syncthreads();
    }
    lbase[t] = sc[t] - lcount[t];
    // phase 2.5: reserve global ranges
    if (t < P) {
        int c = lcount[t];
        gbase[t] = (c > 0) ? atomicAdd(&cursor[t], c) : 0;
    }
    __syncthreads();

    // phase 3: place edges into LDS sorted by partition
    for (int e = start + t; e < end; e += BINB) {
        int r = row[e];
        int c = col[e];
        int part = c >> SHIFT;
        int slot = atomicAdd(&lpos[part], 1);
        lbuf[lbase[part] + slot] = ((unsigned)r << SHIFT) | ((unsigned)c & MASK);
    }
    __syncthreads();

    // phase 4: coalesced flush, one wave per partition round-robin
    int lane = t & 63;
    int wave = t >> 6;
    const int nwaves = BINB / 64;
    for (int part = wave; part < P; part += nwaves) {
        int cnt = lcount[part];
        if (cnt == 0) continue;
        int lb = lbase[part];
        int gb = gbase[part];
        unsigned* dst = binned + (size_t)part * cap;
        for (int j = lane; j < cnt; j += 64) {
            int slot = gb + j;
            if (slot < cap) dst[slot] = lbuf[lb + j];
        }
    }
}

// per-partition: deg from bin (LDS), then p = (W x)*dinv, store p + dinv
__global__ __launch_bounds__(1024) void k_part_node(const unsigned* __restrict__ binned,
                                                    const int* __restrict__ cursor, int cap,
                                                    const float* __restrict__ x,
                                                    const float* __restrict__ conv_w, int n,
                                                    float4* __restrict__ p4,
                                                    float* __restrict__ dinvg) {
    __shared__ int degs[NP];
    __shared__ float w[24];
    int part = blockIdx.x;
    int tid = threadIdx.x;
    if (tid < 24) w[tid] = conv_w[tid];
    if (tid < NP) degs[tid] = 0;
    __syncthreads();
    int cnt = min(cursor[part], cap);
    const unsigned* bin = binned + (size_t)part * cap;
    for (int e = tid; e < cnt; e += 1024)
        atomicAdd(&degs[bin[e] & MASK], 1);
    __syncthreads();
    int base = part * NP;
    int node = base + tid;
    if (tid < NP && node < n) {
        float dinv = rsqrtf((float)(degs[tid] + 1));   // +1 self-loop
        const float* xr = x + (size_t)node * 6;
        float2 a = *(const float2*)xr;
        float2 b = *(const float2*)(xr + 2);
        float2 cc = *(const float2*)(xr + 4);
        float xv[6] = {a.x, a.y, b.x, b.y, cc.x, cc.y};
        float h0 = 0.f, h1 = 0.f, h2 = 0.f, h3 = 0.f;
#pragma unroll
        for (int j = 0; j < 6; ++j) {
            h0 += xv[j] * w[j];
            h1 += xv[j] * w[6 + j];
            h2 += xv[j] * w[12 + j];
            h3 += xv[j] * w[18 + j];
        }
        float4 o;
        o.x = h0 * dinv; o.y = h1 * dinv; o.z = h2 * dinv; o.w = h3 * dinv;
        p4[node] = o;
        dinvg[node] = dinv;
    }
}

// per-partition: accumulate p[row] into LDS tile, tanh, block-reduce -> gsum
__global__ __launch_bounds__(1024) void k_acc(const unsigned* __restrict__ binned,
                                              const int* __restrict__ cursor, int cap,
                                              const float4* __restrict__ p4,
                                              const float* __restrict__ dinvg,
                                              const float* __restrict__ conv_b, int n,
                                              float* __restrict__ gsum) {
    __shared__ float S[NP * 4];          // 16 KB
    __shared__ float4 red[16];
    int part = blockIdx.x;
    int tid = threadIdx.x;
    for (int i = tid; i < NP * 4; i += 1024) S[i] = 0.f;
    __syncthreads();
    int cnt = min(cursor[part], cap);
    const unsigned* bin = binned + (size_t)part * cap;
    for (int e = tid; e < cnt; e += 1024) {
        unsigned v = bin[e];
        float4 pv = p4[v >> SHIFT];
        int local = (int)(v & MASK);
        atomicAdd(&S[local * 4 + 0], pv.x);
        atomicAdd(&S[local * 4 + 1], pv.y);
        atomicAdd(&S[local * 4 + 2], pv.z);
        atomicAdd(&S[local * 4 + 3], pv.w);
    }
    __syncthreads();
    float b0 = conv_b[0], b1 = conv_b[1], b2 = conv_b[2], b3 = conv_b[3];
    float4 acc = {0.f, 0.f, 0.f, 0.f};
    int node = part * NP + tid;
    if (tid < NP && node < n) {
        float di = dinvg[node];
        float4 pv = p4[node];
        acc.x = tanhf(di * (S[tid * 4 + 0] + pv.x) + b0);
        acc.y = tanhf(di * (S[tid * 4 + 1] + pv.y) + b1);
        acc.z = tanhf(di * (S[tid * 4 + 2] + pv.z) + b2);
        acc.w = tanhf(di * (S[tid * 4 + 3] + pv.w) + b3);
    }
#pragma unroll
    for (int off = 32; off > 0; off >>= 1) {
        acc.x += __shfl_down(acc.x, off);
        acc.y += __shfl_down(acc.y, off);
        acc.z += __shfl_down(acc.z, off);
        acc.w += __shfl_down(acc.w, off);
    }
    int lane = tid & 63, wv = tid >> 6;
    if (lane == 0) red[wv] = acc;
    __syncthreads();
    if (tid == 0) {
        float4 tt = red[0];
        for (int k = 1; k < 16; ++k) {
            tt.x += red[k].x; tt.y += red[k].y; tt.z += red[k].z; tt.w += red[k].w;
        }
        unsafeAtomicAdd(&gsum[0], tt.x);
        unsafeAtomicAdd(&gsum[1], tt.y);
        unsafeAtomicAdd(&gsum[2], tt.z);
        unsafeAtomicAdd(&gsum[3], tt.w);
    }
}

__global__ void k_head(const float* __restrict__ gsum,
                       const float* __restrict__ fc1w, const float* __restrict__ fc1b,
                       const float* __restrict__ fc3w, const float* __restrict__ fc3b,
                       float* __restrict__ out, int n) {
    __shared__ float hdn[64];
    int t = threadIdx.x;
    float g[4];
    float inv_n = 1.0f / (float)n;
#pragma unroll
    for (int j = 0; j < 4; ++j) g[j] = gsum[j] * inv_n;
    if (t < 64) {
        float a = fc1b[t];
#pragma unroll
        for (int j = 0; j < 4; ++j) a += g[j] * fc1w[t * 4 + j];
        hdn[t] = fmaxf(a, 0.f);
    }
    __syncthreads();
    if (t < 10) {
        float a = fc3b[t];
#pragma unroll
        for (int k = 0; k < 64; ++k) a += hdn[k] * fc3w[t * 64 + k];
        out[t] = a;
    }
}

// ---------------- fallback path (round-1, global atomics) ----------------

__global__ void k_deg(const int* __restrict__ col, int n_edges, int* __restrict__ deg) {
    int t = blockIdx.x * blockDim.x + threadIdx.x;
    int base = t * 4;
    if (base + 4 <= n_edges) {
        int4 c = *(const int4*)(col + base);
        atomicAdd(&deg[c.x], 1); atomicAdd(&deg[c.y], 1);
        atomicAdd(&deg[c.z], 1); atomicAdd(&deg[c.w], 1);
    } else {
        for (int e = base; e < n_edges; ++e) atomicAdd(&deg[col[e]], 1);
    }
}

__global__ void k_node(const float* __restrict__ x, const float* __restrict__ conv_w,
                       const int* __restrict__ deg, float4* __restrict__ p, int n) {
    int i = blockIdx.x * blockDim.x + threadIdx.x;
    if (i >= n) return;
    const float* xr = x + (size_t)i * 6;
    float2 a = *(const float2*)xr;
    float2 b = *(const float2*)(xr + 2);
    float2 c = *(const float2*)(xr + 4);
    float xv[6] = {a.x, a.y, b.x, b.y, c.x, c.y};
    float dinv = rsqrtf((float)(deg[i] + 1));
    float h0 = 0.f, h1 = 0.f, h2 = 0.f, h3 = 0.f;
#pragma unroll
    for (int j = 0; j < 6; ++j) {
        h0 += xv[j] * conv_w[j];
        h1 += xv[j] * conv_w[6 + j];
        h2 += xv[j] * conv_w[12 + j];
        h3 += xv[j] * conv_w[18 + j];
    }
    float4 o; o.x = h0 * dinv; o.y = h1 * dinv; o.z = h2 * dinv; o.w = h3 * dinv;
    p[i] = o;
}

__global__ void k_scatter(const int* __restrict__ row, const int* __restrict__ col, int n_edges,
                          const float4* __restrict__ p, float* __restrict__ S) {
    int t = blockIdx.x * blockDim.x + threadIdx.x;
    int base = t * 2;
    if (base + 2 <= n_edges) {
        int2 r = *(const int2*)(row + base);
        int2 c = *(const int2*)(col + base);
        float4 p0 = p[r.x], p1 = p[r.y];
        float* s0 = S + 4 * c.x;
        unsafeAtomicAdd(s0 + 0, p0.x); unsafeAtomicAdd(s0 + 1, p0.y);
        unsafeAtomicAdd(s0 + 2, p0.z); unsafeAtomicAdd(s0 + 3, p0.w);
        float* s1 = S + 4 * c.y;
        unsafeAtomicAdd(s1 + 0, p1.x); unsafeAtomicAdd(s1 + 1, p1.y);
        unsafeAtomicAdd(s1 + 2, p1.z); unsafeAtomicAdd(s1 + 3, p1.w);
    } else {
        for (int e = base; e < n_edges; ++e) {
            int r = row[e], c = col[e];
            float4 pv = p[r];
            float* s = S + 4 * c;
            unsafeAtomicAdd(s + 0, pv.x); unsafeAtomicAdd(s + 1, pv.y);
            unsafeAtomicAdd(s + 2, pv.z); unsafeAtomicAdd(s + 3, pv.w);
        }
    }
}

__global__ void k_reduce(const float4* __restrict__ S4, const float4* __restrict__ p,
                         const int* __restrict__ deg, const float* __restrict__ conv_b,
                         int n, float* __restrict__ gsum) {
    int i = blockIdx.x * blockDim.x + threadIdx.x;
    float4 v = {0.f, 0.f, 0.f, 0.f};
    if (i < n) {
        float dinv = rsqrtf((float)(deg[i] + 1));
        float4 s = S4[i];
        float4 pp = p[i];
        v.x = tanhf(dinv * (s.x + pp.x) + conv_b[0]);
        v.y = tanhf(dinv * (s.y + pp.y) + conv_b[1]);
        v.z = tanhf(dinv * (s.z + pp.z) + conv_b[2]);
        v.w = tanhf(dinv * (s.w + pp.w) + conv_b[3]);
    }
#pragma unroll
    for (int off = 32; off > 0; off >>= 1) {
        v.x += __shfl_down(v.x, off);
        v.y += __shfl_down(v.y, off);
        v.z += __shfl_down(v.z, off);
        v.w += __shfl_down(v.w, off);
    }
    __shared__ float4 lds[4];
    int lane = threadIdx.x & 63, w = threadIdx.x >> 6;
    if (lane == 0) lds[w] = v;
    __syncthreads();
    if (threadIdx.x == 0) {
        float4 tt = lds[0];
        for (int k = 1; k < 4; ++k) {
            tt.x += lds[k].x; tt.y += lds[k].y; tt.z += lds[k].z; tt.w += lds[k].w;
        }
        unsafeAtomicAdd(&gsum[0], tt.x); unsafeAtomicAdd(&gsum[1], tt.y);
        unsafeAtomicAdd(&gsum[2], tt.z); unsafeAtomicAdd(&gsum[3], tt.w);
    }
}

// ---------------- launch ----------------

extern "C" void kernel_launch(void* const* d_in, const int* in_sizes, int n_in,
                              void* d_out, int out_size, void* d_ws, size_t ws_size,
                              hipStream_t stream) {
    const float* x      = (const float*)d_in[0];
    const int*   ei     = (const int*)d_in[1];
    const float* conv_w = (const float*)d_in[2];
    const float* conv_b = (const float*)d_in[3];
    const float* fc1w   = (const float*)d_in[4];
    const float* fc1b   = (const float*)d_in[5];
    const float* fc3w   = (const float*)d_in[6];
    const float* fc3b   = (const float*)d_in[7];

    int n = in_sizes[0] / 6;
    int E = in_sizes[1] / 2;
    const int* row = ei;       // edge_index[0] = source
    const int* col = ei + E;   // edge_index[1] = target

    int P = (n + NP - 1) / NP;
    int avg = (E + P - 1) / P;
    int cap = ((avg + avg / 8 + 2048) + 15) & ~15;

    // ws layout (binning path): cursor[P] | gsum[4] | dinv[n] | p4[n] | binned[P*cap]
    size_t off = 0;
    size_t cursor_off = off;          off += (size_t)P * sizeof(int);
    off = (off + 15) & ~(size_t)15;
    size_t gsum_off = off;            off += 4 * sizeof(float);
    size_t zero_end = off;
    off = (off + 15) & ~(size_t)15;
    size_t dinv_off = off;            off += (size_t)n * sizeof(float);
    off = (off + 15) & ~(size_t)15;
    size_t p_off = off;               off += (size_t)n * sizeof(float4);
    off = (off + 15) & ~(size_t)15;
    size_t bin_off = off;             off += (size_t)P * cap * sizeof(unsigned);
    size_t need = off;

    char* ws = (char*)d_ws;
    bool use_bin = (ws_size >= need) && (P <= NPART_MAX) && (n < (1 << 22));

    if (use_bin) {
        int* cursor = (int*)(ws + cursor_off);
        float* gsum = (float*)(ws + gsum_off);
        float* dinvg = (float*)(ws + dinv_off);
        float4* p4 = (float4*)(ws + p_off);
        unsigned* binned = (unsigned*)(ws + bin_off);

        hipMemsetAsync(d_ws, 0, zero_end, stream);
        int bin_blocks = (E + EPB - 1) / EPB;
        k_bin<<<bin_blocks, BINB, 0, stream>>>(row, col, E, P, cap, cursor, binned);
        k_part_node<<<P, 1024, 0, stream>>>(binned, cursor, cap, x, conv_w, n, p4, dinvg);
        k_acc<<<P, 1024, 0, stream>>>(binned, cursor, cap, p4, dinvg, conv_b, n, gsum);
        k_head<<<1, 64, 0, stream>>>(gsum, fc1w, fc1b, fc3w, fc3b, (float*)d_out, n);
    } else {
        size_t o = 0;
        int* deg = (int*)(ws + o);      o += (size_t)n * sizeof(int);
        o = (o + 15) & ~(size_t)15;
        float* S = (float*)(ws + o);    o += (size_t)n * 4 * sizeof(float);
        float* gsum = (float*)(ws + o);
        size_t zend = o + 4 * sizeof(float);
        o = (zend + 15) & ~(size_t)15;
        float4* p = (float4*)(ws + o);

        hipMemsetAsync(d_ws, 0, zend, stream);
        int t1 = (E + 3) / 4;
        k_deg<<<(t1 + 255) / 256, 256, 0, stream>>>(col, E, deg);
        k_node<<<(n + 255) / 256, 256, 0, stream>>>(x, conv_w, deg, p, n);
        int t3 = (E + 1) / 2;
        k_scatter<<<(t3 + 255) / 256, 256, 0, stream>>>(row, col, E, p, S);
        k_reduce<<<(n + 255) / 256, 256, 0, stream>>>((const float4*)S, p, deg, conv_b, n, gsum);
        k_head<<<1, 64, 0, stream>>>(gsum, fc1w, fc1b, fc3w, fc3b, (float*)d_out, n);
    }
}

// Round 4
// 624.545 us; speedup vs baseline: 6.4009x; 1.0698x over previous
//
#include <hip/hip_runtime.h>
#include <hip/hip_fp16.h>
#include <math.h>

// GCN forward: GCNConv(6->4, self-loops, sym-norm) -> tanh -> mean-pool -> fc1+relu -> fc3
// agg[c] = dinv[c] * ( sum_{edges r->c} p[r] + p[c] ) + conv_b, p[i] = (W x[i]) * dinv[i]
//
// R4: (a) p-table compressed to fp16x4 (4 MB -> fits per-XCD L2; R3 k_acc fetched 540 MB
// because the 8 MB fp32 table thrashed the 4 MB L2); (b) uint4 bin loads, 4 gathers in
// flight per thread; (c) S-tile LDS stride 5 (stride 4 hit only 8 banks -> 8-way conflict).

constexpr int NP = 1024;        // nodes per partition
constexpr int SHIFT = 10;
constexpr unsigned MASK = 1023;
constexpr int NPART_MAX = 512;  // scan width; P = ceil(500k/1024) = 489
constexpr int EPB = 8192;       // edges per k_bin block
constexpr int BINB = 512;       // k_bin block size
constexpr int BT = 512;         // per-partition kernel block size

struct alignas(8) Half4 { __half2 a, b; };

// ---------------- binning path ----------------

__global__ __launch_bounds__(BINB) void k_bin(const int* __restrict__ row,
                                              const int* __restrict__ col, int E,
                                              int P, int cap, int* __restrict__ cursor,
                                              unsigned* __restrict__ binned) {
    __shared__ unsigned lbuf[EPB];          // 32 KB, sorted-by-partition edge buffer
    __shared__ int lcount[NPART_MAX];
    __shared__ int lbase[NPART_MAX];
    __shared__ int gbase[NPART_MAX];
    __shared__ int lpos[NPART_MAX];
    __shared__ int sc[NPART_MAX];

    int t = threadIdx.x;
    int start = blockIdx.x * EPB;
    int end = min(start + EPB, E);
    bool full = (end - start) == EPB;

    lcount[t] = 0; lpos[t] = 0;
    __syncthreads();

    // phase 1: count per partition (vectorized)
    if (full) {
        const int4* c4 = (const int4*)(col + start);
#pragma unroll
        for (int i = 0; i < EPB / 4 / BINB; ++i) {
            int4 c = c4[t + i * BINB];
            atomicAdd(&lcount[c.x >> SHIFT], 1);
            atomicAdd(&lcount[c.y >> SHIFT], 1);
            atomicAdd(&lcount[c.z >> SHIFT], 1);
            atomicAdd(&lcount[c.w >> SHIFT], 1);
        }
    } else {
        for (int e = start + t; e < end; e += BINB)
            atomicAdd(&lcount[col[e] >> SHIFT], 1);
    }
    __syncthreads();

    // phase 2: exclusive scan (Hillis-Steele, 512 wide)
    sc[t] = lcount[t];
    __syncthreads();
    for (int off = 1; off < NPART_MAX; off <<= 1) {
        int v = (t >= off) ? sc[t - off] : 0;
        __syncthreads();
        sc[t] += v;
        __syncthreads();
    }
    lbase[t] = sc[t] - lcount[t];
    if (t < P) {
        int c = lcount[t];
        gbase[t] = (c > 0) ? atomicAdd(&cursor[t], c) : 0;
    }
    __syncthreads();

    // phase 3: place edges into LDS sorted by partition
    if (full) {
        const int4* c4 = (const int4*)(col + start);
        const int4* r4 = (const int4*)(row + start);
#pragma unroll
        for (int i = 0; i < EPB / 4 / BINB; ++i) {
            int4 c = c4[t + i * BINB];
            int4 r = r4[t + i * BINB];
            int part, slot;
            part = c.x >> SHIFT; slot = atomicAdd(&lpos[part], 1);
            lbuf[lbase[part] + slot] = ((unsigned)r.x << SHIFT) | ((unsigned)c.x & MASK);
            part = c.y >> SHIFT; slot = atomicAdd(&lpos[part], 1);
            lbuf[lbase[part] + slot] = ((unsigned)r.y << SHIFT) | ((unsigned)c.y & MASK);
            part = c.z >> SHIFT; slot = atomicAdd(&lpos[part], 1);
            lbuf[lbase[part] + slot] = ((unsigned)r.z << SHIFT) | ((unsigned)c.z & MASK);
            part = c.w >> SHIFT; slot = atomicAdd(&lpos[part], 1);
            lbuf[lbase[part] + slot] = ((unsigned)r.w << SHIFT) | ((unsigned)c.w & MASK);
        }
    } else {
        for (int e = start + t; e < end; e += BINB) {
            int r = row[e], c = col[e];
            int part = c >> SHIFT;
            int slot = atomicAdd(&lpos[part], 1);
            lbuf[lbase[part] + slot] = ((unsigned)r << SHIFT) | ((unsigned)c & MASK);
        }
    }
    __syncthreads();

    // phase 4: coalesced flush, one wave per partition round-robin
    int lane = t & 63;
    int wave = t >> 6;
    const int nwaves = BINB / 64;
    for (int part = wave; part < P; part += nwaves) {
        int cnt = lcount[part];
        if (cnt == 0) continue;
        int lb = lbase[part];
        int gb = gbase[part];
        unsigned* dst = binned + (size_t)part * cap;
        for (int j = lane; j < cnt; j += 64) {
            int slot = gb + j;
            if (slot < cap) dst[slot] = lbuf[lb + j];
        }
    }
}

// per-partition: deg from bin (LDS), then p = (W x)*dinv -> fp16x4, store dinv
__global__ __launch_bounds__(BT) void k_part_node(const unsigned* __restrict__ binned,
                                                  const int* __restrict__ cursor, int cap,
                                                  const float* __restrict__ x,
                                                  const float* __restrict__ conv_w, int n,
                                                  Half4* __restrict__ ph,
                                                  float* __restrict__ dinvg) {
    __shared__ int degs[NP];
    __shared__ float w[24];
    int part = blockIdx.x;
    int tid = threadIdx.x;
    if (tid < 24) w[tid] = conv_w[tid];
    for (int i = tid; i < NP; i += BT) degs[i] = 0;
    __syncthreads();
    int cnt = min(cursor[part], cap);
    const unsigned* bin = binned + (size_t)part * cap;
    const uint4* bin4 = (const uint4*)bin;
    int cnt4 = cnt >> 2;
    for (int i = tid; i < cnt4; i += BT) {
        uint4 v = bin4[i];
        atomicAdd(&degs[v.x & MASK], 1);
        atomicAdd(&degs[v.y & MASK], 1);
        atomicAdd(&degs[v.z & MASK], 1);
        atomicAdd(&degs[v.w & MASK], 1);
    }
    for (int e = (cnt4 << 2) + tid; e < cnt; e += BT)
        atomicAdd(&degs[bin[e] & MASK], 1);
    __syncthreads();
    int base = part * NP;
    for (int i = tid; i < NP; i += BT) {
        int node = base + i;
        if (node >= n) continue;
        float dinv = rsqrtf((float)(degs[i] + 1));   // +1 self-loop
        const float* xr = x + (size_t)node * 6;
        float2 a = *(const float2*)xr;
        float2 b = *(const float2*)(xr + 2);
        float2 cc = *(const float2*)(xr + 4);
        float xv[6] = {a.x, a.y, b.x, b.y, cc.x, cc.y};
        float h0 = 0.f, h1 = 0.f, h2 = 0.f, h3 = 0.f;
#pragma unroll
        for (int j = 0; j < 6; ++j) {
            h0 += xv[j] * w[j];
            h1 += xv[j] * w[6 + j];
            h2 += xv[j] * w[12 + j];
            h3 += xv[j] * w[18 + j];
        }
        Half4 o;
        o.a = __floats2half2_rn(h0 * dinv, h1 * dinv);
        o.b = __floats2half2_rn(h2 * dinv, h3 * dinv);
        ph[node] = o;
        dinvg[node] = dinv;
    }
}

// per-partition: accumulate p[row] into LDS tile (stride 5), tanh, block-reduce -> gsum
__global__ __launch_bounds__(BT) void k_acc(const unsigned* __restrict__ binned,
                                            const int* __restrict__ cursor, int cap,
                                            const Half4* __restrict__ ph,
                                            const float* __restrict__ dinvg,
                                            const float* __restrict__ conv_b, int n,
                                            float* __restrict__ gsum) {
    __shared__ float S[NP * 5];          // 20 KB, stride 5 (coprime with 32 banks)
    __shared__ float4 red[BT / 64];
    int part = blockIdx.x;
    int tid = threadIdx.x;
    for (int i = tid; i < NP * 5; i += BT) S[i] = 0.f;
    __syncthreads();
    int cnt = min(cursor[part], cap);
    const unsigned* bin = binned + (size_t)part * cap;
    const uint4* bin4 = (const uint4*)bin;
    int cnt4 = cnt >> 2;
    for (int i = tid; i < cnt4; i += BT) {
        uint4 v = bin4[i];
        Half4 h0 = ph[v.x >> SHIFT];   // 4 independent 8 B gathers in flight
        Half4 h1 = ph[v.y >> SHIFT];
        Half4 h2 = ph[v.z >> SHIFT];
        Half4 h3 = ph[v.w >> SHIFT];
        float2 a, b; float* s;
        a = __half22float2(h0.a); b = __half22float2(h0.b); s = &S[(v.x & MASK) * 5];
        atomicAdd(s + 0, a.x); atomicAdd(s + 1, a.y); atomicAdd(s + 2, b.x); atomicAdd(s + 3, b.y);
        a = __half22float2(h1.a); b = __half22float2(h1.b); s = &S[(v.y & MASK) * 5];
        atomicAdd(s + 0, a.x); atomicAdd(s + 1, a.y); atomicAdd(s + 2, b.x); atomicAdd(s + 3, b.y);
        a = __half22float2(h2.a); b = __half22float2(h2.b); s = &S[(v.z & MASK) * 5];
        atomicAdd(s + 0, a.x); atomicAdd(s + 1, a.y); atomicAdd(s + 2, b.x); atomicAdd(s + 3, b.y);
        a = __half22float2(h3.a); b = __half22float2(h3.b); s = &S[(v.w & MASK) * 5];
        atomicAdd(s + 0, a.x); atomicAdd(s + 1, a.y); atomicAdd(s + 2, b.x); atomicAdd(s + 3, b.y);
    }
    for (int e = (cnt4 << 2) + tid; e < cnt; e += BT) {
        unsigned v = bin[e];
        Half4 h = ph[v >> SHIFT];
        float2 a = __half22float2(h.a), b = __half22float2(h.b);
        float* s = &S[(v & MASK) * 5];
        atomicAdd(s + 0, a.x); atomicAdd(s + 1, a.y); atomicAdd(s + 2, b.x); atomicAdd(s + 3, b.y);
    }
    __syncthreads();
    float b0 = conv_b[0], b1 = conv_b[1], b2 = conv_b[2], b3 = conv_b[3];
    float4 acc = {0.f, 0.f, 0.f, 0.f};
    int base = part * NP;
    for (int i = tid; i < NP; i += BT) {
        int node = base + i;
        if (node >= n) continue;
        float di = dinvg[node];
        Half4 hp = ph[node];
        float2 pa = __half22float2(hp.a), pb = __half22float2(hp.b);
        acc.x += tanhf(di * (S[i * 5 + 0] + pa.x) + b0);
        acc.y += tanhf(di * (S[i * 5 + 1] + pa.y) + b1);
        acc.z += tanhf(di * (S[i * 5 + 2] + pb.x) + b2);
        acc.w += tanhf(di * (S[i * 5 + 3] + pb.y) + b3);
    }
#pragma unroll
    for (int off = 32; off > 0; off >>= 1) {
        acc.x += __shfl_down(acc.x, off);
        acc.y += __shfl_down(acc.y, off);
        acc.z += __shfl_down(acc.z, off);
        acc.w += __shfl_down(acc.w, off);
    }
    int lane = tid & 63, wv = tid >> 6;
    if (lane == 0) red[wv] = acc;
    __syncthreads();
    if (tid == 0) {
        float4 tt = red[0];
        for (int k = 1; k < BT / 64; ++k) {
            tt.x += red[k].x; tt.y += red[k].y; tt.z += red[k].z; tt.w += red[k].w;
        }
        unsafeAtomicAdd(&gsum[0], tt.x);
        unsafeAtomicAdd(&gsum[1], tt.y);
        unsafeAtomicAdd(&gsum[2], tt.z);
        unsafeAtomicAdd(&gsum[3], tt.w);
    }
}

__global__ void k_head(const float* __restrict__ gsum,
                       const float* __restrict__ fc1w, const float* __restrict__ fc1b,
                       const float* __restrict__ fc3w, const float* __restrict__ fc3b,
                       float* __restrict__ out, int n) {
    __shared__ float hdn[64];
    int t = threadIdx.x;
    float g[4];
    float inv_n = 1.0f / (float)n;
#pragma unroll
    for (int j = 0; j < 4; ++j) g[j] = gsum[j] * inv_n;
    if (t < 64) {
        float a = fc1b[t];
#pragma unroll
        for (int j = 0; j < 4; ++j) a += g[j] * fc1w[t * 4 + j];
        hdn[t] = fmaxf(a, 0.f);
    }
    __syncthreads();
    if (t < 10) {
        float a = fc3b[t];
#pragma unroll
        for (int k = 0; k < 64; ++k) a += hdn[k] * fc3w[t * 64 + k];
        out[t] = a;
    }
}

// ---------------- fallback path (round-1, global atomics) ----------------

__global__ void k_deg(const int* __restrict__ col, int n_edges, int* __restrict__ deg) {
    int t = blockIdx.x * blockDim.x + threadIdx.x;
    int base = t * 4;
    if (base + 4 <= n_edges) {
        int4 c = *(const int4*)(col + base);
        atomicAdd(&deg[c.x], 1); atomicAdd(&deg[c.y], 1);
        atomicAdd(&deg[c.z], 1); atomicAdd(&deg[c.w], 1);
    } else {
        for (int e = base; e < n_edges; ++e) atomicAdd(&deg[col[e]], 1);
    }
}

__global__ void k_node(const float* __restrict__ x, const float* __restrict__ conv_w,
                       const int* __restrict__ deg, float4* __restrict__ p, int n) {
    int i = blockIdx.x * blockDim.x + threadIdx.x;
    if (i >= n) return;
    const float* xr = x + (size_t)i * 6;
    float2 a = *(const float2*)xr;
    float2 b = *(const float2*)(xr + 2);
    float2 c = *(const float2*)(xr + 4);
    float xv[6] = {a.x, a.y, b.x, b.y, c.x, c.y};
    float dinv = rsqrtf((float)(deg[i] + 1));
    float h0 = 0.f, h1 = 0.f, h2 = 0.f, h3 = 0.f;
#pragma unroll
    for (int j = 0; j < 6; ++j) {
        h0 += xv[j] * conv_w[j];
        h1 += xv[j] * conv_w[6 + j];
        h2 += xv[j] * conv_w[12 + j];
        h3 += xv[j] * conv_w[18 + j];
    }
    float4 o; o.x = h0 * dinv; o.y = h1 * dinv; o.z = h2 * dinv; o.w = h3 * dinv;
    p[i] = o;
}

__global__ void k_scatter(const int* __restrict__ row, const int* __restrict__ col, int n_edges,
                          const float4* __restrict__ p, float* __restrict__ S) {
    int t = blockIdx.x * blockDim.x + threadIdx.x;
    int base = t * 2;
    if (base + 2 <= n_edges) {
        int2 r = *(const int2*)(row + base);
        int2 c = *(const int2*)(col + base);
        float4 p0 = p[r.x], p1 = p[r.y];
        float* s0 = S + 4 * c.x;
        unsafeAtomicAdd(s0 + 0, p0.x); unsafeAtomicAdd(s0 + 1, p0.y);
        unsafeAtomicAdd(s0 + 2, p0.z); unsafeAtomicAdd(s0 + 3, p0.w);
        float* s1 = S + 4 * c.y;
        unsafeAtomicAdd(s1 + 0, p1.x); unsafeAtomicAdd(s1 + 1, p1.y);
        unsafeAtomicAdd(s1 + 2, p1.z); unsafeAtomicAdd(s1 + 3, p1.w);
    } else {
        for (int e = base; e < n_edges; ++e) {
            int r = row[e], c = col[e];
            float4 pv = p[r];
            float* s = S + 4 * c;
            unsafeAtomicAdd(s + 0, pv.x); unsafeAtomicAdd(s + 1, pv.y);
            unsafeAtomicAdd(s + 2, pv.z); unsafeAtomicAdd(s + 3, pv.w);
        }
    }
}

__global__ void k_reduce(const float4* __restrict__ S4, const float4* __restrict__ p,
                         const int* __restrict__ deg, const float* __restrict__ conv_b,
                         int n, float* __restrict__ gsum) {
    int i = blockIdx.x * blockDim.x + threadIdx.x;
    float4 v = {0.f, 0.f, 0.f, 0.f};
    if (i < n) {
        float dinv = rsqrtf((float)(deg[i] + 1));
        float4 s = S4[i];
        float4 pp = p[i];
        v.x = tanhf(dinv * (s.x + pp.x) + conv_b[0]);
        v.y = tanhf(dinv * (s.y + pp.y) + conv_b[1]);
        v.z = tanhf(dinv * (s.z + pp.z) + conv_b[2]);
        v.w = tanhf(dinv * (s.w + pp.w) + conv_b[3]);
    }
#pragma unroll
    for (int off = 32; off > 0; off >>= 1) {
        v.x += __shfl_down(v.x, off);
        v.y += __shfl_down(v.y, off);
        v.z += __shfl_down(v.z, off);
        v.w += __shfl_down(v.w, off);
    }
    __shared__ float4 lds[4];
    int lane = threadIdx.x & 63, w = threadIdx.x >> 6;
    if (lane == 0) lds[w] = v;
    __syncthreads();
    if (threadIdx.x == 0) {
        float4 tt = lds[0];
        for (int k = 1; k < 4; ++k) {
            tt.x += lds[k].x; tt.y += lds[k].y; tt.z += lds[k].z; tt.w += lds[k].w;
        }
        unsafeAtomicAdd(&gsum[0], tt.x); unsafeAtomicAdd(&gsum[1], tt.y);
        unsafeAtomicAdd(&gsum[2], tt.z); unsafeAtomicAdd(&gsum[3], tt.w);
    }
}

// ---------------- launch ----------------

extern "C" void kernel_launch(void* const* d_in, const int* in_sizes, int n_in,
                              void* d_out, int out_size, void* d_ws, size_t ws_size,
                              hipStream_t stream) {
    const float* x      = (const float*)d_in[0];
    const int*   ei     = (const int*)d_in[1];
    const float* conv_w = (const float*)d_in[2];
    const float* conv_b = (const float*)d_in[3];
    const float* fc1w   = (const float*)d_in[4];
    const float* fc1b   = (const float*)d_in[5];
    const float* fc3w   = (const float*)d_in[6];
    const float* fc3b   = (const float*)d_in[7];

    int n = in_sizes[0] / 6;
    int E = in_sizes[1] / 2;
    const int* row = ei;       // edge_index[0] = source
    const int* col = ei + E;   // edge_index[1] = target

    int P = (n + NP - 1) / NP;
    int avg = (E + P - 1) / P;
    int cap = ((avg + avg / 8 + 2048) + 15) & ~15;

    // ws layout: cursor[P] | gsum[4] | dinv[n] | ph[n] (fp16x4) | binned[P*cap]
    size_t off = 0;
    size_t cursor_off = off;          off += (size_t)P * sizeof(int);
    off = (off + 15) & ~(size_t)15;
    size_t gsum_off = off;            off += 4 * sizeof(float);
    size_t zero_end = off;
    off = (off + 15) & ~(size_t)15;
    size_t dinv_off = off;            off += (size_t)n * sizeof(float);
    off = (off + 15) & ~(size_t)15;
    size_t ph_off = off;              off += (size_t)n * sizeof(Half4);
    off = (off + 15) & ~(size_t)15;
    size_t bin_off = off;             off += (size_t)P * cap * sizeof(unsigned);
    size_t need = off;

    char* ws = (char*)d_ws;
    bool use_bin = (ws_size >= need) && (P <= NPART_MAX) && (n < (1 << 22));

    if (use_bin) {
        int* cursor = (int*)(ws + cursor_off);
        float* gsum = (float*)(ws + gsum_off);
        float* dinvg = (float*)(ws + dinv_off);
        Half4* ph = (Half4*)(ws + ph_off);
        unsigned* binned = (unsigned*)(ws + bin_off);

        hipMemsetAsync(d_ws, 0, zero_end, stream);
        int bin_blocks = (E + EPB - 1) / EPB;
        k_bin<<<bin_blocks, BINB, 0, stream>>>(row, col, E, P, cap, cursor, binned);
        k_part_node<<<P, BT, 0, stream>>>(binned, cursor, cap, x, conv_w, n, ph, dinvg);
        k_acc<<<P, BT, 0, stream>>>(binned, cursor, cap, ph, dinvg, conv_b, n, gsum);
        k_head<<<1, 64, 0, stream>>>(gsum, fc1w, fc1b, fc3w, fc3b, (float*)d_out, n);
    } else {
        size_t o = 0;
        int* deg = (int*)(ws + o);      o += (size_t)n * sizeof(int);
        o = (o + 15) & ~(size_t)15;
        float* S = (float*)(ws + o);    o += (size_t)n * 4 * sizeof(float);
        float* gsum = (float*)(ws + o);
        size_t zend = o + 4 * sizeof(float);
        o = (zend + 15) & ~(size_t)15;
        float4* p = (float4*)(ws + o);

        hipMemsetAsync(d_ws, 0, zend, stream);
        int t1 = (E + 3) / 4;
        k_deg<<<(t1 + 255) / 256, 256, 0, stream>>>(col, E, deg);
        k_node<<<(n + 255) / 256, 256, 0, stream>>>(x, conv_w, deg, p, n);
        int t3 = (E + 1) / 2;
        k_scatter<<<(t3 + 255) / 256, 256, 0, stream>>>(row, col, E, p, S);
        k_reduce<<<(n + 255) / 256, 256, 0, stream>>>((const float4*)S, p, deg, conv_b, n, gsum);
        k_head<<<1, 64, 0, stream>>>(gsum, fc1w, fc1b, fc3w, fc3b, (float*)d_out, n);
    }
}